// Round 7
// baseline (641.877 us; speedup 1.0000x reference)
//
#include <hip/hip_runtime.h>
#include <stdint.h>

#define HDIM 2048
#define FFND 8192
#define NHEAD 16
#define HDHEAD 128
#define TSEQ 2048
#define MTOK 4096

typedef short s16;
typedef __bf16 bf16;
typedef __attribute__((ext_vector_type(8))) __bf16 bf16x8;
typedef __attribute__((ext_vector_type(4))) float f32x4;

__device__ __forceinline__ unsigned short f2bf(float f) {
    union { float f; unsigned u; } a; a.f = f;
    unsigned r = a.u + 0x7fffu + ((a.u >> 16) & 1u);
    return (unsigned short)(r >> 16);
}

__device__ __forceinline__ void gload_lds16(const s16* g, void* l) {
    __builtin_amdgcn_global_load_lds(
        (const __attribute__((address_space(1))) void*)g,
        (__attribute__((address_space(3))) void*)l, 16, 0, 0);
}

// ---------------- transpose + fp32->bf16 convert: out[n][k] = bf16(in[k][n]) ----------------
__global__ __launch_bounds__(256) void transpose_convert(
    const float* __restrict__ in, s16* __restrict__ out, int K, int N)
{
    __shared__ float tile[32][33];
    int n0 = blockIdx.x * 32, k0 = blockIdx.y * 32;
    int tx = threadIdx.x, ty = threadIdx.y;
    #pragma unroll
    for (int r = 0; r < 32; r += 8)
        tile[ty + r][tx] = in[(size_t)(k0 + ty + r) * N + n0 + tx];
    __syncthreads();
    #pragma unroll
    for (int r = 0; r < 32; r += 8)
        out[(size_t)(n0 + ty + r) * K + k0 + tx] = (s16)f2bf(tile[tx][ty + r]);
}

// ---------------- LayerNorm (fp32 in -> bf16 out), one row per block ----------------
__global__ __launch_bounds__(256) void ln_kernel(
    const float* __restrict__ x, const float* __restrict__ gam,
    const float* __restrict__ bet, s16* __restrict__ out)
{
    int row = blockIdx.x;
    int t = threadIdx.x;
    const float4* xr = (const float4*)(x + (size_t)row * HDIM);
    float4 v0 = xr[t], v1 = xr[t + 256];
    float s = v0.x + v0.y + v0.z + v0.w + v1.x + v1.y + v1.z + v1.w;
    #pragma unroll
    for (int m = 1; m < 64; m <<= 1) s += __shfl_xor(s, m);
    __shared__ float red[8];
    int wid = t >> 6, lane = t & 63;
    if (lane == 0) red[wid] = s;
    __syncthreads();
    float mean = (red[0] + red[1] + red[2] + red[3]) * (1.0f / HDIM);
    float d0 = v0.x - mean, d1 = v0.y - mean, d2 = v0.z - mean, d3 = v0.w - mean;
    float d4 = v1.x - mean, d5 = v1.y - mean, d6 = v1.z - mean, d7 = v1.w - mean;
    float vs = d0*d0 + d1*d1 + d2*d2 + d3*d3 + d4*d4 + d5*d5 + d6*d6 + d7*d7;
    #pragma unroll
    for (int m = 1; m < 64; m <<= 1) vs += __shfl_xor(vs, m);
    if (lane == 0) red[4 + wid] = vs;
    __syncthreads();
    float var = (red[4] + red[5] + red[6] + red[7]) * (1.0f / HDIM);
    float rinv = rsqrtf(var + 1e-5f);
    const float4* gm = (const float4*)gam;
    const float4* bt = (const float4*)bet;
    float4 g0 = gm[t], g1 = gm[t + 256], b0 = bt[t], b1 = bt[t + 256];
    s16* orow = out + (size_t)row * HDIM;
    float y0 = d0 * rinv * g0.x + b0.x, y1 = d1 * rinv * g0.y + b0.y;
    float y2 = d2 * rinv * g0.z + b0.z, y3 = d3 * rinv * g0.w + b0.w;
    float y4 = d4 * rinv * g1.x + b1.x, y5 = d5 * rinv * g1.y + b1.y;
    float y6 = d6 * rinv * g1.z + b1.z, y7 = d7 * rinv * g1.w + b1.w;
    uint2 o0, o1;
    o0.x = (unsigned)f2bf(y0) | ((unsigned)f2bf(y1) << 16);
    o0.y = (unsigned)f2bf(y2) | ((unsigned)f2bf(y3) << 16);
    o1.x = (unsigned)f2bf(y4) | ((unsigned)f2bf(y5) << 16);
    o1.y = (unsigned)f2bf(y6) | ((unsigned)f2bf(y7) << 16);
    *(uint2*)(orow + t * 4) = o0;
    *(uint2*)(orow + 1024 + t * 4) = o1;
}

// ============ 4-phase/K-tile BMxBN GEMM (m201 cadence + r6 read economy) ============
// C[M][N] = A[M][K](bf16) * Bt[N][K]^T + bias.  BK=64.  8 waves: WN=BN/64, WM=8/WN,
// wave tile MS x 64 (MS = BM/WM). Phase (mh,kh): <=8 ds_reads + 2 stages + barrier +
// lgkm(0) + (HF*4) MFMA + barrier. Stage sched: P0:A01(T+1,e) P1:A23(T+1,e)
// P2:B23(T+1,e) P3:B01(T+2,d) -> uniform counted vmcnt(2) at P3 tail (never 0 mid-loop).
// 3-bit XOR involution swizzle (zero-conflict, validated r2-r6).
// EPI 0: qkv scatter via LDS bounce. EPI 1: fp32 +bias+resid. EPI 2: bf16 gelu.
template<int BM, int BN, int EPI>
__global__ __launch_bounds__(512, 2) void gemm4p(
    const s16* __restrict__ A, const s16* __restrict__ Bt,
    const float* __restrict__ bias, int M, int N, int K,
    float* __restrict__ of, const float* __restrict__ resid,
    s16* __restrict__ ob, s16* __restrict__ ob2, s16* __restrict__ ob3)
{
    constexpr int WN  = BN / 64;          // waves in N (4|2)
    constexpr int WM  = 8 / WN;           // waves in M (2|4)
    constexpr int MS  = BM / WM;          // wave M-span (128|64)
    constexpr int HF  = MS / 32;          // A frags per phase (4|2)
    constexpr int NMI = 2 * HF;
    constexpr int AU  = BM / 64;          // A stage units (4|2)
    constexpr int NBU = BN / 64;          // B stage units (4|2)
    constexpr int ABYT = BM * 128;
    constexpr int DBUF = ABYT + BN * 128;
    __shared__ __attribute__((aligned(16))) char smem[2 * DBUF];

    int t = threadIdx.x;
    int wid = t >> 6, lane = t & 63;
    int wm = (BN == 256) ? (wid >> 2) : (wid >> 1);
    int wn = (BN == 256) ? (wid & 3) : (wid & 1);
    int c = lane & 15, g = lane >> 4;

    // bijective XCD swizzle (all grids %8==0)
    int gx = gridDim.x;
    int wg = blockIdx.y * gx + blockIdx.x;
    int nwg = gx * gridDim.y;
    wg = (wg & 7) * (nwg >> 3) + (wg >> 3);
    int n0 = (wg % gx) * BN;
    int m0 = (wg / gx) * BM;

    // bias to regs BEFORE staging (vmcnt cleanliness)
    float bn[4];
    #pragma unroll
    for (int ni = 0; ni < 4; ++ni) bn[ni] = bias[n0 + wn * 64 + ni * 16 + c];

    // staging: thread covers 16B at (unit row slr, phys slot t&7); source col pre-swizzled
    int slr = t >> 3;
    int sls = (t & 7) ^ (slr & 7);
    auto stA = [&](int d, int u, int T) {
        gload_lds16(A + (size_t)(m0 + u * 64 + slr) * K + T * 64 + sls * 8,
                    smem + d * DBUF + u * 8192 + t * 16);
    };
    auto stB = [&](int d, int u, int T) {
        gload_lds16(Bt + (size_t)(n0 + u * 64 + slr) * K + T * 64 + sls * 8,
                    smem + d * DBUF + ABYT + u * 8192 + t * 16);
    };

    // fragment-read swizzled 16B slot offsets (k-half 0: slots 0-3, k-half 1: 4-7)
    int px0 = ((g) ^ (c & 7)) * 16;
    int px1 = ((4 + g) ^ (c & 7)) * 16;

    f32x4 zero = {0.f, 0.f, 0.f, 0.f};
    f32x4 acc[NMI][4];
    #pragma unroll
    for (int mi = 0; mi < NMI; ++mi)
        #pragma unroll
        for (int ni = 0; ni < 4; ++ni) acc[mi][ni] = zero;

    bf16x8 a[HF], bfr[4];

#define READ_B(d, kh) { _Pragma("unroll") for (int fn = 0; fn < 4; ++fn) \
    bfr[fn] = *(const bf16x8*)(smem + (d) * DBUF + ABYT + \
        (wn * 64 + fn * 16 + c) * 128 + ((kh) ? px1 : px0)); }
#define READ_A(d, mh, kh) { _Pragma("unroll") for (int f = 0; f < HF; ++f) \
    a[f] = *(const bf16x8*)(smem + (d) * DBUF + \
        (wm * MS + ((mh) * HF + f) * 16 + c) * 128 + ((kh) ? px1 : px0)); }
#define MFMA_PH(mh) { _Pragma("unroll") for (int f = 0; f < HF; ++f) \
    _Pragma("unroll") for (int ni = 0; ni < 4; ++ni) \
        acc[(mh) * HF + f][ni] = __builtin_amdgcn_mfma_f32_16x16x32_bf16( \
            a[f], bfr[ni], acc[(mh) * HF + f][ni], 0, 0, 0); }
#define PH_OPEN  __builtin_amdgcn_s_barrier(); \
    asm volatile("s_waitcnt lgkmcnt(0)" ::: "memory"); \
    __builtin_amdgcn_sched_barrier(0); \
    __builtin_amdgcn_s_setprio(1);
#define PH_CLOSE __builtin_amdgcn_s_setprio(0); __builtin_amdgcn_s_barrier();

    int nk = K >> 6;

    // prologue: tile0 full into d0 + B01(t1) into d1 (FIFO seeds steady state)
    #pragma unroll
    for (int u = 0; u < AU; ++u) stA(0, u, 0);
    #pragma unroll
    for (int u = 0; u < NBU; ++u) stB(0, u, 0);
    stB(1, 0, 1); stB(1, 1, 1);
    asm volatile("s_waitcnt vmcnt(2)" ::: "memory");   // tile0 landed (this wave)
    __builtin_amdgcn_s_barrier();                       // ... for ALL waves

    for (int T = 0; T < nk; ++T) {
        int d = T & 1, e = d ^ 1;
        bool s1 = (T + 1 < nk), s2 = (T + 2 < nk);
        // P0 (m0,k0): stage A01(T+1)
        READ_B(d, 0) READ_A(d, 0, 0)
        if (s1) { stA(e, 0, T + 1); stA(e, 1, T + 1); }
        PH_OPEN MFMA_PH(0) PH_CLOSE
        // P1 (m1,k0): stage A23(T+1) if AU==4
        READ_A(d, 1, 0)
        if constexpr (AU == 4) { if (s1) { stA(e, 2, T + 1); stA(e, 3, T + 1); } }
        PH_OPEN MFMA_PH(1) PH_CLOSE
        // P2 (m0,k1): stage B23(T+1) if NBU==4
        READ_B(d, 1) READ_A(d, 0, 1)
        if constexpr (NBU == 4) { if (s1) { stB(e, 2, T + 1); stB(e, 3, T + 1); } }
        PH_OPEN MFMA_PH(0) PH_CLOSE
        // P3 (m1,k1): stage B01(T+2) into d (P3 window reads A only -> no conflict)
        READ_A(d, 1, 1)
        if (s2) { stB(d, 0, T + 2); stB(d, 1, T + 2); }
        PH_OPEN MFMA_PH(1)
        __builtin_amdgcn_s_setprio(0);
        if (s2) { asm volatile("s_waitcnt vmcnt(2)" ::: "memory"); }
        else    { asm volatile("s_waitcnt vmcnt(0)" ::: "memory"); }
        __builtin_amdgcn_s_barrier();
    }
#undef READ_B
#undef READ_A
#undef MFMA_PH
#undef PH_OPEN
#undef PH_CLOSE

    // epilogue: acc[mi][ni]: row = m0 + wm*MS + mi*16 + g*4 + j, col = n0 + wn*64 + ni*16 + c
    if constexpr (EPI == 0) {
        constexpr int ROWG = BM / 64;
        int part = n0 >> 11;
        int hh0 = (n0 & 2047) >> 7;
        int bb = m0 >> 11;
        int tt0 = m0 & 2047;
        s16* LT = (s16*)smem;           // 64 x 264 bounce
        #pragma unroll
        for (int q2 = 0; q2 < ROWG; ++q2) {
            if (q2) __syncthreads();
            bool sel = (MS == 128) ? (wm == (q2 >> 1)) : (wm == q2);
            int fb = (MS == 128) ? (q2 & 1) * 4 : 0;
            if (sel) {
                #pragma unroll
                for (int f = 0; f < 4; ++f)
                    #pragma unroll
                    for (int ni = 0; ni < 4; ++ni)
                        #pragma unroll
                        for (int j = 0; j < 4; ++j)
                            LT[(f * 16 + g * 4 + j) * 264 + wn * 64 + ni * 16 + c] =
                                (s16)f2bf(acc[fb + f][ni][j] + bn[ni]);
            }
            __syncthreads();
            if (part < 2) {
                s16* dst = (part == 0 ? ob : ob2);
                int rr = t >> 3, c0 = (t & 7) * 32;
                int hh = hh0 + (c0 >> 7);
                size_t base = (((size_t)(bb * NHEAD + hh)) * TSEQ + tt0 + q2 * 64 + rr) * HDHEAD + (c0 & 127);
                #pragma unroll
                for (int k2 = 0; k2 < 4; ++k2)
                    *(bf16x8*)(dst + base + k2 * 8) = *(const bf16x8*)(LT + rr * 264 + c0 + k2 * 8);
            } else {
                int ddl = t >> 1, half = t & 1;
                int hh = hh0 + (ddl >> 7);
                size_t base = (((size_t)(bb * NHEAD + hh)) * HDHEAD + (ddl & 127)) * TSEQ + tt0 + q2 * 64 + half * 32;
                #pragma unroll
                for (int k2 = 0; k2 < 4; ++k2) {
                    union { s16 v[8]; bf16x8 x; } u;
                    #pragma unroll
                    for (int e = 0; e < 8; ++e) u.v[e] = LT[(half * 32 + k2 * 8 + e) * 264 + ddl];
                    *(bf16x8*)(ob3 + base + k2 * 8) = u.x;
                }
            }
        }
    } else {
        #pragma unroll
        for (int mi = 0; mi < NMI; ++mi) {
            #pragma unroll
            for (int ni = 0; ni < 4; ++ni) {
                int n = n0 + wn * 64 + ni * 16 + c;
                #pragma unroll
                for (int j = 0; j < 4; ++j) {
                    int m = m0 + wm * MS + mi * 16 + g * 4 + j;
                    float val = acc[mi][ni][j] + bn[ni];
                    if constexpr (EPI == 1) {
                        size_t idx = (size_t)m * N + n;
                        of[idx] = val + resid[idx];
                    } else {
                        float zz = 1.5957691216057308f * (val + 0.044715f * val * val * val);
                        float ge = val / (1.0f + __expf(-zz));
                        ob[(size_t)m * N + n] = (s16)f2bf(ge);
                    }
                }
            }
        }
    }
}

// ---------------- causal flash attention, swapped-operand (S^T = K*Q^T) ----------------
__global__ __launch_bounds__(256) void attn_kernel(
    const s16* __restrict__ qb, const s16* __restrict__ kbf,
    const s16* __restrict__ vbf, s16* __restrict__ yb)
{
    __shared__ __attribute__((aligned(16))) s16 Kl[64 * 128];
    __shared__ __attribute__((aligned(16))) s16 Vl[128 * 64];
    int bid0 = blockIdx.x;
    int bid = ((bid0 & 7) << 7) | (bid0 >> 3);   // XCD swizzle (1024 blocks)
    int qt = bid & 31;
    int bh = bid >> 5;
    int q0 = qt << 6;
    int t = threadIdx.x;
    int wid = t >> 6, lane = t & 63;
    int c = lane & 15, g = lane >> 4;

    const s16* qrow = qb + ((size_t)bh * TSEQ + q0 + wid * 16 + c) * HDHEAD;
    bf16x8 qf[4];
    #pragma unroll
    for (int ds = 0; ds < 4; ++ds) qf[ds] = *(const bf16x8*)(qrow + ds * 32 + g * 8);

    f32x4 zero = {0.f, 0.f, 0.f, 0.f};
    f32x4 acc_o[8];
    #pragma unroll
    for (int o = 0; o < 8; ++o) acc_o[o] = zero;
    float mrun = -INFINITY, lrun = 0.0f;
    const float sc = 0.08838834764831843f;

    int tr = t >> 4, tcb = (t & 15) << 4;
    int vr = t >> 3, vcb = (t & 7) << 4;
    const s16* ksrc = kbf + (size_t)bh * TSEQ * HDHEAD;
    const s16* vsrc = vbf + (size_t)bh * HDHEAD * TSEQ;
    int qg = q0 + wid * 16 + c;

    for (int kt = 0; kt <= qt; ++kt) {
        __syncthreads();
        #pragma unroll
        for (int rr = 0; rr < 4; ++rr) {
            int row = tr + rr * 16;
            bf16x8 kv = *(const bf16x8*)(ksrc + (size_t)(kt * 64 + row) * HDHEAD + (tcb >> 1));
            *(bf16x8*)((char*)Kl + row * 256 + (tcb ^ ((row & 7) << 4))) = kv;
        }
        #pragma unroll
        for (int rr = 0; rr < 4; ++rr) {
            int row = vr + rr * 32;
            bf16x8 vv = *(const bf16x8*)(vsrc + (size_t)row * TSEQ + kt * 64 + (vcb >> 1));
            *(bf16x8*)((char*)Vl + row * 128 + (vcb ^ ((row & 7) << 4))) = vv;
        }
        __syncthreads();

        f32x4 sacc[4];
        #pragma unroll
        for (int kb2 = 0; kb2 < 4; ++kb2) sacc[kb2] = zero;
        #pragma unroll
        for (int ds = 0; ds < 4; ++ds) {
            #pragma unroll
            for (int kb2 = 0; kb2 < 4; ++kb2) {
                int krow = kb2 * 16 + c;
                bf16x8 kf = *(const bf16x8*)((char*)Kl + krow * 256 +
                                ((ds * 64 + g * 16) ^ ((krow & 7) << 4)));
                sacc[kb2] = __builtin_amdgcn_mfma_f32_16x16x32_bf16(kf, qf[ds], sacc[kb2], 0, 0, 0);
            }
        }
        float pv[16];
        float mt = -INFINITY;
        bool diag = (kt == qt);
        #pragma unroll
        for (int kb2 = 0; kb2 < 4; ++kb2) {
            #pragma unroll
            for (int j = 0; j < 4; ++j) {
                float s = sacc[kb2][j] * sc;
                if (diag && (kt * 64 + kb2 * 16 + g * 4 + j) > qg) s = -INFINITY;
                pv[kb2 * 4 + j] = s;
                mt = fmaxf(mt, s);
            }
        }
        mt = fmaxf(mt, __shfl_xor(mt, 16));
        mt = fmaxf(mt, __shfl_xor(mt, 32));
        float mnew = fmaxf(mrun, mt);
        float corr = __expf(mrun - mnew);
        float ls = 0.0f;
        #pragma unroll
        for (int i = 0; i < 16; ++i) { float p = __expf(pv[i] - mnew); pv[i] = p; ls += p; }
        ls += __shfl_xor(ls, 16);
        ls += __shfl_xor(ls, 32);
        lrun = lrun * corr + ls;
        mrun = mnew;
        #pragma unroll
        for (int o = 0; o < 8; ++o)
            #pragma unroll
            for (int j = 0; j < 4; ++j) acc_o[o][j] *= corr;

        unsigned dpk[8];
        #pragma unroll
        for (int kb2 = 0; kb2 < 4; ++kb2) {
            dpk[kb2 * 2]     = (unsigned)f2bf(pv[kb2 * 4 + 0]) | ((unsigned)f2bf(pv[kb2 * 4 + 1]) << 16);
            dpk[kb2 * 2 + 1] = (unsigned)f2bf(pv[kb2 * 4 + 2]) | ((unsigned)f2bf(pv[kb2 * 4 + 3]) << 16);
        }
        int srcA = ((g & 1) << 5) + c;
        int srcB = srcA + 16;
        #pragma unroll
        for (int s2 = 0; s2 < 2; ++s2) {
            unsigned lo0 = (unsigned)__shfl((int)dpk[(2 * s2) * 2 + 0], srcA);
            unsigned hi0 = (unsigned)__shfl((int)dpk[(2 * s2 + 1) * 2 + 0], srcA);
            unsigned lo1 = (unsigned)__shfl((int)dpk[(2 * s2) * 2 + 1], srcA);
            unsigned hi1 = (unsigned)__shfl((int)dpk[(2 * s2 + 1) * 2 + 1], srcA);
            unsigned lo2 = (unsigned)__shfl((int)dpk[(2 * s2) * 2 + 0], srcB);
            unsigned hi2 = (unsigned)__shfl((int)dpk[(2 * s2 + 1) * 2 + 0], srcB);
            unsigned lo3 = (unsigned)__shfl((int)dpk[(2 * s2) * 2 + 1], srcB);
            unsigned hi3 = (unsigned)__shfl((int)dpk[(2 * s2 + 1) * 2 + 1], srcB);
            union { unsigned u[4]; bf16x8 v; } pf;
            pf.u[0] = (g < 2) ? lo0 : hi0;
            pf.u[1] = (g < 2) ? lo1 : hi1;
            pf.u[2] = (g < 2) ? lo2 : hi2;
            pf.u[3] = (g < 2) ? lo3 : hi3;
            #pragma unroll
            for (int o = 0; o < 8; ++o) {
                int vrow = o * 16 + c;
                bf16x8 vf = *(const bf16x8*)((char*)Vl + vrow * 128 +
                                ((s2 * 64 + g * 16) ^ ((vrow & 7) << 4)));
                acc_o[o] = __builtin_amdgcn_mfma_f32_16x16x32_bf16(vf, pf.v, acc_o[o], 0, 0, 0);
            }
        }
    }

    float inv = 1.0f / lrun;
    int bb = bh >> 4, hh = bh & 15;
    s16* yp = yb + ((size_t)bb * TSEQ + q0 + wid * 16 + c) * HDIM + hh * HDHEAD;
    #pragma unroll
    for (int o = 0; o < 8; ++o) {
        int d = o * 16 + g * 4;
        unsigned p0 = (unsigned)f2bf(acc_o[o][0] * inv) | ((unsigned)f2bf(acc_o[o][1] * inv) << 16);
        unsigned p1 = (unsigned)f2bf(acc_o[o][2] * inv) | ((unsigned)f2bf(acc_o[o][3] * inv) << 16);
        *(unsigned*)(yp + d) = p0;
        *(unsigned*)(yp + d + 2) = p1;
    }
}

extern "C" void kernel_launch(void* const* d_in, const int* in_sizes, int n_in,
                              void* d_out, int out_size, void* d_ws, size_t ws_size,
                              hipStream_t stream)
{
    const float* x     = (const float*)d_in[0];
    const float* ln1g  = (const float*)d_in[1];
    const float* ln1b  = (const float*)d_in[2];
    const float* wattn = (const float*)d_in[3];
    const float* battn = (const float*)d_in[4];
    const float* wproj = (const float*)d_in[5];
    const float* bproj = (const float*)d_in[6];
    const float* ln2g  = (const float*)d_in[7];
    const float* ln2b  = (const float*)d_in[8];
    const float* wfc   = (const float*)d_in[9];
    const float* bfc   = (const float*)d_in[10];
    const float* wfc2  = (const float*)d_in[11];
    const float* bfc2  = (const float*)d_in[12];
    float* out = (float*)d_out;

    s16* ws   = (s16*)d_ws;
    s16* wT   = ws;                        // 16,777,216 elems (max weight^T)
    s16* qbuf = wT + 16777216;             // 8,388,608
    s16* kbuf = qbuf + 8388608;            // 8,388,608
    s16* vbuf = kbuf + 8388608;            // 8,388,608 (transposed V)
    s16* hbuf = vbuf + 8388608;            // 8,388,608 (LN1 out; reused as attn y)
    s16* ybuf  = hbuf;
    s16* h2buf = qbuf;
    s16* gbuf  = kbuf;

    // 1) LN1
    ln_kernel<<<4096, 256, 0, stream>>>(x, ln1g, ln1b, hbuf);
    // 2) QKV GEMM (BM=128 -> grid 768 = 3 blocks/CU balanced; scatter q/k/v, v transposed)
    transpose_convert<<<dim3(6144 / 32, 2048 / 32), dim3(32, 8), 0, stream>>>(wattn, wT, 2048, 6144);
    gemm4p<128, 256, 0><<<dim3(6144 / 256, 4096 / 128), 512, 0, stream>>>(
        hbuf, wT, battn, MTOK, 6144, 2048, nullptr, nullptr, qbuf, kbuf, vbuf);
    // 3) attention
    attn_kernel<<<1024, 256, 0, stream>>>(qbuf, kbuf, vbuf, ybuf);
    // 4) proj (+residual, fp32 -> d_out)
    transpose_convert<<<dim3(2048 / 32, 2048 / 32), dim3(32, 8), 0, stream>>>(wproj, wT, 2048, 2048);
    gemm4p<256, 128, 1><<<dim3(2048 / 128, 4096 / 256), 512, 0, stream>>>(
        ybuf, wT, bproj, MTOK, 2048, 2048, out, x, nullptr, nullptr, nullptr);
    // 5) LN2
    ln_kernel<<<4096, 256, 0, stream>>>(out, ln2g, ln2b, h2buf);
    // 6) fc (+gelu, bf16)
    transpose_convert<<<dim3(8192 / 32, 2048 / 32), dim3(32, 8), 0, stream>>>(wfc, wT, 2048, 8192);
    gemm4p<256, 256, 2><<<dim3(8192 / 256, 4096 / 256), 512, 0, stream>>>(
        h2buf, wT, bfc, MTOK, 8192, 2048, nullptr, nullptr, gbuf, nullptr, nullptr);
    // 7) fc2 (+residual, fp32; reads+overwrites d_out per-element)
    transpose_convert<<<dim3(2048 / 32, 8192 / 32), dim3(32, 8), 0, stream>>>(wfc2, wT, 8192, 2048);
    gemm4p<256, 128, 1><<<dim3(2048 / 128, 4096 / 256), 512, 0, stream>>>(
        gbuf, wT, bfc2, MTOK, 2048, 8192, out, out, nullptr, nullptr, nullptr);
}

// Round 8
// 615.548 us; speedup vs baseline: 1.0428x; 1.0428x over previous
//
#include <hip/hip_runtime.h>
#include <stdint.h>

#define HDIM 2048
#define FFND 8192
#define NHEAD 16
#define HDHEAD 128
#define TSEQ 2048
#define MTOK 4096

typedef short s16;
typedef __bf16 bf16;
typedef __attribute__((ext_vector_type(8))) __bf16 bf16x8;
typedef __attribute__((ext_vector_type(4))) float f32x4;

__device__ __forceinline__ unsigned short f2bf(float f) {
    union { float f; unsigned u; } a; a.f = f;
    unsigned r = a.u + 0x7fffu + ((a.u >> 16) & 1u);
    return (unsigned short)(r >> 16);
}

__device__ __forceinline__ void gload_lds16(const s16* g, void* l) {
    __builtin_amdgcn_global_load_lds(
        (const __attribute__((address_space(1))) void*)g,
        (__attribute__((address_space(3))) void*)l, 16, 0, 0);
}

// ---------------- transpose + fp32->bf16 convert: out[n][k] = bf16(in[k][n]) ----------------
__global__ __launch_bounds__(256) void transpose_convert(
    const float* __restrict__ in, s16* __restrict__ out, int K, int N)
{
    __shared__ float tile[32][33];
    int n0 = blockIdx.x * 32, k0 = blockIdx.y * 32;
    int tx = threadIdx.x, ty = threadIdx.y;
    #pragma unroll
    for (int r = 0; r < 32; r += 8)
        tile[ty + r][tx] = in[(size_t)(k0 + ty + r) * N + n0 + tx];
    __syncthreads();
    #pragma unroll
    for (int r = 0; r < 32; r += 8)
        out[(size_t)(n0 + ty + r) * K + k0 + tx] = (s16)f2bf(tile[tx][ty + r]);
}

// ---------------- LayerNorm (fp32 in -> bf16 out), one row per block ----------------
__global__ __launch_bounds__(256) void ln_kernel(
    const float* __restrict__ x, const float* __restrict__ gam,
    const float* __restrict__ bet, s16* __restrict__ out)
{
    int row = blockIdx.x;
    int t = threadIdx.x;
    const float4* xr = (const float4*)(x + (size_t)row * HDIM);
    float4 v0 = xr[t], v1 = xr[t + 256];
    float s = v0.x + v0.y + v0.z + v0.w + v1.x + v1.y + v1.z + v1.w;
    #pragma unroll
    for (int m = 1; m < 64; m <<= 1) s += __shfl_xor(s, m);
    __shared__ float red[8];
    int wid = t >> 6, lane = t & 63;
    if (lane == 0) red[wid] = s;
    __syncthreads();
    float mean = (red[0] + red[1] + red[2] + red[3]) * (1.0f / HDIM);
    float d0 = v0.x - mean, d1 = v0.y - mean, d2 = v0.z - mean, d3 = v0.w - mean;
    float d4 = v1.x - mean, d5 = v1.y - mean, d6 = v1.z - mean, d7 = v1.w - mean;
    float vs = d0*d0 + d1*d1 + d2*d2 + d3*d3 + d4*d4 + d5*d5 + d6*d6 + d7*d7;
    #pragma unroll
    for (int m = 1; m < 64; m <<= 1) vs += __shfl_xor(vs, m);
    if (lane == 0) red[4 + wid] = vs;
    __syncthreads();
    float var = (red[4] + red[5] + red[6] + red[7]) * (1.0f / HDIM);
    float rinv = rsqrtf(var + 1e-5f);
    const float4* gm = (const float4*)gam;
    const float4* bt = (const float4*)bet;
    float4 g0 = gm[t], g1 = gm[t + 256], b0 = bt[t], b1 = bt[t + 256];
    s16* orow = out + (size_t)row * HDIM;
    float y0 = d0 * rinv * g0.x + b0.x, y1 = d1 * rinv * g0.y + b0.y;
    float y2 = d2 * rinv * g0.z + b0.z, y3 = d3 * rinv * g0.w + b0.w;
    float y4 = d4 * rinv * g1.x + b1.x, y5 = d5 * rinv * g1.y + b1.y;
    float y6 = d6 * rinv * g1.z + b1.z, y7 = d7 * rinv * g1.w + b1.w;
    uint2 o0, o1;
    o0.x = (unsigned)f2bf(y0) | ((unsigned)f2bf(y1) << 16);
    o0.y = (unsigned)f2bf(y2) | ((unsigned)f2bf(y3) << 16);
    o1.x = (unsigned)f2bf(y4) | ((unsigned)f2bf(y5) << 16);
    o1.y = (unsigned)f2bf(y6) | ((unsigned)f2bf(y7) << 16);
    *(uint2*)(orow + t * 4) = o0;
    *(uint2*)(orow + 1024 + t * 4) = o1;
}

// ============ 2-phase/K-tile BMxBN GEMM (r6 structure, BM generalized) ============
// C[M][N] = A[M][K](bf16) * Bt[N][K]^T + bias.  BK=64.  8 waves, WN=BN/64, WM=8/WN,
// wave tile MS x 64 (MS=BM/WM). B held in regs (read once/tile). Phase A: all reads
// (set1=B+A-half0 then set2=A-half1, order-pinned), stage SA(T+1 -> idle buf e),
// lgkm(LG1), MFMA half0, barrier. Phase B: stage SB(T+2 -> current buf d, set1-certified
// regions only), lgkm(0), MFMA half1, counted vmcnt(VMN) (never 0 mid-loop), barrier.
// (256,256): SA={A1,A3} SB={A0,A2,B0-3} VMN=6 LG1=8  [r6-identical]
// (128,256): SA={A0,A1} SB={B0-3}       VMN=4 LG1=4  [QKV balanced: 768 blocks]
// (256,128): SA={A0-A3} SB={B0,B1}      VMN=2 LG1=4  [r6-identical]
// 3-bit XOR involution swizzle (zero-conflict, validated r2-r7).
template<int BM, int BN, int EPI>
__global__ __launch_bounds__(512, 2) void gemm2p(
    const s16* __restrict__ A, const s16* __restrict__ Bt,
    const float* __restrict__ bias, int M, int N, int K,
    float* __restrict__ of, const float* __restrict__ resid,
    s16* __restrict__ ob, s16* __restrict__ ob2, s16* __restrict__ ob3)
{
    constexpr int WN  = BN / 64;
    constexpr int WM  = 8 / WN;
    constexpr int MS  = BM / WM;                  // 128|64
    constexpr int NMI = MS / 16;
    constexpr int HF  = NMI / 2;
    constexpr int AU  = BM / 64;
    constexpr int NBU = BN / 64;
    constexpr int ABYT = BM * 128;
    constexpr int DBUF = ABYT + BN * 128;
    constexpr bool BIG = (BM == 256 && BN == 256);
    constexpr int VMN = BIG ? 6 : (BN == 256 ? 4 : 2);
    constexpr int LG1 = BIG ? 8 : 4;
    __shared__ __attribute__((aligned(16))) char smem[2 * DBUF];

    int t = threadIdx.x;
    int wid = t >> 6, lane = t & 63;
    int wm = (WN == 4) ? (wid >> 2) : (wid >> 1);
    int wn = (WN == 4) ? (wid & 3) : (wid & 1);
    int c = lane & 15, g = lane >> 4;

    // bijective XCD swizzle (all grids %8==0)
    int gx = gridDim.x;
    int wg = blockIdx.y * gx + blockIdx.x;
    int nwg = gx * gridDim.y;
    wg = (wg & 7) * (nwg >> 3) + (wg >> 3);
    int n0 = (wg % gx) * BN;
    int m0 = (wg / gx) * BM;

    // bias to regs BEFORE staging (vmcnt cleanliness)
    float bn[4];
    #pragma unroll
    for (int ni = 0; ni < 4; ++ni) bn[ni] = bias[n0 + wn * 64 + ni * 16 + c];

    // staging: thread covers 16B at (unit row slr, phys slot t&7); source col pre-swizzled
    int slr = t >> 3;
    int sls = (t & 7) ^ (slr & 7);
    auto stA = [&](int d, int u, int T) {
        gload_lds16(A + (size_t)(m0 + u * 64 + slr) * K + T * 64 + sls * 8,
                    smem + d * DBUF + u * 8192 + t * 16);
    };
    auto stB = [&](int d, int u, int T) {
        gload_lds16(Bt + (size_t)(n0 + u * 64 + slr) * K + T * 64 + sls * 8,
                    smem + d * DBUF + ABYT + u * 8192 + t * 16);
    };
    // SB: set1-certified regions -> staged into CURRENT buffer d for T+2
    auto stageSB = [&](int d, int T) {
        if constexpr (BIG) {
            stA(d, 0, T); stA(d, 2, T);
            stB(d, 0, T); stB(d, 1, T); stB(d, 2, T); stB(d, 3, T);
        } else if constexpr (BN == 256) {
            stB(d, 0, T); stB(d, 1, T); stB(d, 2, T); stB(d, 3, T);
        } else {
            stB(d, 0, T); stB(d, 1, T);
        }
    };
    // SA: staged into IDLE buffer e for T+1 (always race-free)
    auto stageSA = [&](int d, int T) {
        if constexpr (BIG) { stA(d, 1, T); stA(d, 3, T); }
        else if constexpr (BN == 256) { stA(d, 0, T); stA(d, 1, T); }
        else { stA(d, 0, T); stA(d, 1, T); stA(d, 2, T); stA(d, 3, T); }
    };

    // fragment-read swizzled 16B slot offsets; row&7 == c&7
    int px0 = ((g) ^ (c & 7)) * 16;
    int px1 = ((4 + g) ^ (c & 7)) * 16;

    f32x4 zero = {0.f, 0.f, 0.f, 0.f};
    f32x4 acc[NMI][4];
    #pragma unroll
    for (int mi = 0; mi < NMI; ++mi)
        #pragma unroll
        for (int ni = 0; ni < 4; ++ni) acc[mi][ni] = zero;

    bf16x8 a0[HF][2], a1[HF][2], bfr[4][2];

#define READ_B(d) { _Pragma("unroll") for (int fn = 0; fn < 4; ++fn) { \
    const char* p_ = smem + (d) * DBUF + ABYT + (wn * 64 + fn * 16 + c) * 128; \
    bfr[fn][0] = *(const bf16x8*)(p_ + px0); \
    bfr[fn][1] = *(const bf16x8*)(p_ + px1); } }
#define READ_A(d, h, arr) { _Pragma("unroll") for (int f = 0; f < HF; ++f) { \
    const char* p_ = smem + (d) * DBUF + (wm * MS + ((h) * HF + f) * 16 + c) * 128; \
    arr[f][0] = *(const bf16x8*)(p_ + px0); \
    arr[f][1] = *(const bf16x8*)(p_ + px1); } }
#define MFMA_H(h, arr) { _Pragma("unroll") for (int f = 0; f < HF; ++f) \
    _Pragma("unroll") for (int ni = 0; ni < 4; ++ni) { \
        acc[(h)*HF+f][ni] = __builtin_amdgcn_mfma_f32_16x16x32_bf16( \
            arr[f][0], bfr[ni][0], acc[(h)*HF+f][ni], 0, 0, 0); \
        acc[(h)*HF+f][ni] = __builtin_amdgcn_mfma_f32_16x16x32_bf16( \
            arr[f][1], bfr[ni][1], acc[(h)*HF+f][ni], 0, 0, 0); } }

    int nk = K >> 6;

    // prologue (FIFO order matches steady state): tile0 full, then SB(t1)
    stageSB(0, 0);
    stageSA(0, 0);
    stageSB(1, 1);
    asm volatile("s_waitcnt vmcnt(%0)" :: "i"(VMN) : "memory");   // tile0 landed (this wave)
    __builtin_amdgcn_s_barrier();                                  // ... for ALL waves

    for (int T = 0; T < nk; ++T) {
        int d = T & 1;
        bool s1 = (T + 1 < nk), s2 = (T + 2 < nk);
        // ---- phase A: all reads + SA stage + MFMA half0 ----
        __builtin_amdgcn_sched_barrier(0);
        READ_B(d) READ_A(d, 0, a0)
        __builtin_amdgcn_sched_barrier(0);   // pin set1 < set2 issue order
        READ_A(d, 1, a1)
        if (s1) stageSA(d ^ 1, T + 1);
        asm volatile("s_waitcnt lgkmcnt(%0)" :: "i"(LG1) : "memory");  // set1 done
        __builtin_amdgcn_sched_barrier(0);
        __builtin_amdgcn_s_setprio(1);
        MFMA_H(0, a0)
        __builtin_amdgcn_s_setprio(0);
        __builtin_amdgcn_s_barrier();        // certifies set1 reads for all waves
        __builtin_amdgcn_sched_barrier(0);
        // ---- phase B: SB stage + MFMA half1 ----
        if (s2) stageSB(d, T + 2);
        asm volatile("s_waitcnt lgkmcnt(0)" ::: "memory");             // set2 done
        __builtin_amdgcn_sched_barrier(0);
        __builtin_amdgcn_s_setprio(1);
        MFMA_H(1, a1)
        __builtin_amdgcn_s_setprio(0);
        if (s2) { asm volatile("s_waitcnt vmcnt(%0)" :: "i"(VMN) : "memory"); }
        else    { asm volatile("s_waitcnt vmcnt(0)" ::: "memory"); }
        __builtin_amdgcn_s_barrier();        // tile T+1 published
        __builtin_amdgcn_sched_barrier(0);
    }
#undef READ_B
#undef READ_A
#undef MFMA_H

    // epilogue: acc[mi][ni]: row = m0 + wm*MS + mi*16 + g*4 + j, col = n0 + wn*64 + ni*16 + c
    if constexpr (EPI == 0) {
        constexpr int ROWG = BM / 64;
        int part = n0 >> 11;
        int hh0 = (n0 & 2047) >> 7;
        int bb = m0 >> 11;
        int tt0 = m0 & 2047;
        s16* LT = (s16*)smem;           // 64 x 264 bounce
        #pragma unroll
        for (int q2 = 0; q2 < ROWG; ++q2) {
            if (q2) __syncthreads();
            bool sel = (MS == 128) ? (wm == (q2 >> 1)) : (wm == q2);
            int fb = (MS == 128) ? (q2 & 1) * 4 : 0;
            if (sel) {
                #pragma unroll
                for (int f = 0; f < 4; ++f)
                    #pragma unroll
                    for (int ni = 0; ni < 4; ++ni)
                        #pragma unroll
                        for (int j = 0; j < 4; ++j)
                            LT[(f * 16 + g * 4 + j) * 264 + wn * 64 + ni * 16 + c] =
                                (s16)f2bf(acc[fb + f][ni][j] + bn[ni]);
            }
            __syncthreads();
            if (part < 2) {
                s16* dst = (part == 0 ? ob : ob2);
                int rr = t >> 3, c0 = (t & 7) * 32;
                int hh = hh0 + (c0 >> 7);
                size_t base = (((size_t)(bb * NHEAD + hh)) * TSEQ + tt0 + q2 * 64 + rr) * HDHEAD + (c0 & 127);
                #pragma unroll
                for (int k2 = 0; k2 < 4; ++k2)
                    *(bf16x8*)(dst + base + k2 * 8) = *(const bf16x8*)(LT + rr * 264 + c0 + k2 * 8);
            } else {
                int ddl = t >> 1, half = t & 1;
                int hh = hh0 + (ddl >> 7);
                size_t base = (((size_t)(bb * NHEAD + hh)) * HDHEAD + (ddl & 127)) * TSEQ + tt0 + q2 * 64 + half * 32;
                #pragma unroll
                for (int k2 = 0; k2 < 4; ++k2) {
                    union { s16 v[8]; bf16x8 x; } u;
                    #pragma unroll
                    for (int e = 0; e < 8; ++e) u.v[e] = LT[(half * 32 + k2 * 8 + e) * 264 + ddl];
                    *(bf16x8*)(ob3 + base + k2 * 8) = u.x;
                }
            }
        }
    } else {
        #pragma unroll
        for (int mi = 0; mi < NMI; ++mi) {
            #pragma unroll
            for (int ni = 0; ni < 4; ++ni) {
                int n = n0 + wn * 64 + ni * 16 + c;
                #pragma unroll
                for (int j = 0; j < 4; ++j) {
                    int m = m0 + wm * MS + mi * 16 + g * 4 + j;
                    float val = acc[mi][ni][j] + bn[ni];
                    if constexpr (EPI == 1) {
                        size_t idx = (size_t)m * N + n;
                        of[idx] = val + resid[idx];
                    } else {
                        float zz = 1.5957691216057308f * (val + 0.044715f * val * val * val);
                        float ge = val / (1.0f + __expf(-zz));
                        ob[(size_t)m * N + n] = (s16)f2bf(ge);
                    }
                }
            }
        }
    }
}

// ---------------- causal flash attention, swapped-operand (S^T = K*Q^T) ----------------
__global__ __launch_bounds__(256) void attn_kernel(
    const s16* __restrict__ qb, const s16* __restrict__ kbf,
    const s16* __restrict__ vbf, s16* __restrict__ yb)
{
    __shared__ __attribute__((aligned(16))) s16 Kl[64 * 128];
    __shared__ __attribute__((aligned(16))) s16 Vl[128 * 64];
    int bid0 = blockIdx.x;
    int bid = ((bid0 & 7) << 7) | (bid0 >> 3);   // XCD swizzle (1024 blocks)
    int qt = bid & 31;
    int bh = bid >> 5;
    int q0 = qt << 6;
    int t = threadIdx.x;
    int wid = t >> 6, lane = t & 63;
    int c = lane & 15, g = lane >> 4;

    const s16* qrow = qb + ((size_t)bh * TSEQ + q0 + wid * 16 + c) * HDHEAD;
    bf16x8 qf[4];
    #pragma unroll
    for (int ds = 0; ds < 4; ++ds) qf[ds] = *(const bf16x8*)(qrow + ds * 32 + g * 8);

    f32x4 zero = {0.f, 0.f, 0.f, 0.f};
    f32x4 acc_o[8];
    #pragma unroll
    for (int o = 0; o < 8; ++o) acc_o[o] = zero;
    float mrun = -INFINITY, lrun = 0.0f;
    const float sc = 0.08838834764831843f;

    int tr = t >> 4, tcb = (t & 15) << 4;
    int vr = t >> 3, vcb = (t & 7) << 4;
    const s16* ksrc = kbf + (size_t)bh * TSEQ * HDHEAD;
    const s16* vsrc = vbf + (size_t)bh * HDHEAD * TSEQ;
    int qg = q0 + wid * 16 + c;

    for (int kt = 0; kt <= qt; ++kt) {
        __syncthreads();
        #pragma unroll
        for (int rr = 0; rr < 4; ++rr) {
            int row = tr + rr * 16;
            bf16x8 kv = *(const bf16x8*)(ksrc + (size_t)(kt * 64 + row) * HDHEAD + (tcb >> 1));
            *(bf16x8*)((char*)Kl + row * 256 + (tcb ^ ((row & 7) << 4))) = kv;
        }
        #pragma unroll
        for (int rr = 0; rr < 4; ++rr) {
            int row = vr + rr * 32;
            bf16x8 vv = *(const bf16x8*)(vsrc + (size_t)row * TSEQ + kt * 64 + (vcb >> 1));
            *(bf16x8*)((char*)Vl + row * 128 + (vcb ^ ((row & 7) << 4))) = vv;
        }
        __syncthreads();

        f32x4 sacc[4];
        #pragma unroll
        for (int kb2 = 0; kb2 < 4; ++kb2) sacc[kb2] = zero;
        #pragma unroll
        for (int ds = 0; ds < 4; ++ds) {
            #pragma unroll
            for (int kb2 = 0; kb2 < 4; ++kb2) {
                int krow = kb2 * 16 + c;
                bf16x8 kf = *(const bf16x8*)((char*)Kl + krow * 256 +
                                ((ds * 64 + g * 16) ^ ((krow & 7) << 4)));
                sacc[kb2] = __builtin_amdgcn_mfma_f32_16x16x32_bf16(kf, qf[ds], sacc[kb2], 0, 0, 0);
            }
        }
        float pv[16];
        float mt = -INFINITY;
        bool diag = (kt == qt);
        #pragma unroll
        for (int kb2 = 0; kb2 < 4; ++kb2) {
            #pragma unroll
            for (int j = 0; j < 4; ++j) {
                float s = sacc[kb2][j] * sc;
                if (diag && (kt * 64 + kb2 * 16 + g * 4 + j) > qg) s = -INFINITY;
                pv[kb2 * 4 + j] = s;
                mt = fmaxf(mt, s);
            }
        }
        mt = fmaxf(mt, __shfl_xor(mt, 16));
        mt = fmaxf(mt, __shfl_xor(mt, 32));
        float mnew = fmaxf(mrun, mt);
        float corr = __expf(mrun - mnew);
        float ls = 0.0f;
        #pragma unroll
        for (int i = 0; i < 16; ++i) { float p = __expf(pv[i] - mnew); pv[i] = p; ls += p; }
        ls += __shfl_xor(ls, 16);
        ls += __shfl_xor(ls, 32);
        lrun = lrun * corr + ls;
        mrun = mnew;
        #pragma unroll
        for (int o = 0; o < 8; ++o)
            #pragma unroll
            for (int j = 0; j < 4; ++j) acc_o[o][j] *= corr;

        unsigned dpk[8];
        #pragma unroll
        for (int kb2 = 0; kb2 < 4; ++kb2) {
            dpk[kb2 * 2]     = (unsigned)f2bf(pv[kb2 * 4 + 0]) | ((unsigned)f2bf(pv[kb2 * 4 + 1]) << 16);
            dpk[kb2 * 2 + 1] = (unsigned)f2bf(pv[kb2 * 4 + 2]) | ((unsigned)f2bf(pv[kb2 * 4 + 3]) << 16);
        }
        int srcA = ((g & 1) << 5) + c;
        int srcB = srcA + 16;
        #pragma unroll
        for (int s2 = 0; s2 < 2; ++s2) {
            unsigned lo0 = (unsigned)__shfl((int)dpk[(2 * s2) * 2 + 0], srcA);
            unsigned hi0 = (unsigned)__shfl((int)dpk[(2 * s2 + 1) * 2 + 0], srcA);
            unsigned lo1 = (unsigned)__shfl((int)dpk[(2 * s2) * 2 + 1], srcA);
            unsigned hi1 = (unsigned)__shfl((int)dpk[(2 * s2 + 1) * 2 + 1], srcA);
            unsigned lo2 = (unsigned)__shfl((int)dpk[(2 * s2) * 2 + 0], srcB);
            unsigned hi2 = (unsigned)__shfl((int)dpk[(2 * s2 + 1) * 2 + 0], srcB);
            unsigned lo3 = (unsigned)__shfl((int)dpk[(2 * s2) * 2 + 1], srcB);
            unsigned hi3 = (unsigned)__shfl((int)dpk[(2 * s2 + 1) * 2 + 1], srcB);
            union { unsigned u[4]; bf16x8 v; } pf;
            pf.u[0] = (g < 2) ? lo0 : hi0;
            pf.u[1] = (g < 2) ? lo1 : hi1;
            pf.u[2] = (g < 2) ? lo2 : hi2;
            pf.u[3] = (g < 2) ? lo3 : hi3;
            #pragma unroll
            for (int o = 0; o < 8; ++o) {
                int vrow = o * 16 + c;
                bf16x8 vf = *(const bf16x8*)((char*)Vl + vrow * 128 +
                                ((s2 * 64 + g * 16) ^ ((vrow & 7) << 4)));
                acc_o[o] = __builtin_amdgcn_mfma_f32_16x16x32_bf16(vf, pf.v, acc_o[o], 0, 0, 0);
            }
        }
    }

    float inv = 1.0f / lrun;
    int bb = bh >> 4, hh = bh & 15;
    s16* yp = yb + ((size_t)bb * TSEQ + q0 + wid * 16 + c) * HDIM + hh * HDHEAD;
    #pragma unroll
    for (int o = 0; o < 8; ++o) {
        int d = o * 16 + g * 4;
        unsigned p0 = (unsigned)f2bf(acc_o[o][0] * inv) | ((unsigned)f2bf(acc_o[o][1] * inv) << 16);
        unsigned p1 = (unsigned)f2bf(acc_o[o][2] * inv) | ((unsigned)f2bf(acc_o[o][3] * inv) << 16);
        *(unsigned*)(yp + d) = p0;
        *(unsigned*)(yp + d + 2) = p1;
    }
}

extern "C" void kernel_launch(void* const* d_in, const int* in_sizes, int n_in,
                              void* d_out, int out_size, void* d_ws, size_t ws_size,
                              hipStream_t stream)
{
    const float* x     = (const float*)d_in[0];
    const float* ln1g  = (const float*)d_in[1];
    const float* ln1b  = (const float*)d_in[2];
    const float* wattn = (const float*)d_in[3];
    const float* battn = (const float*)d_in[4];
    const float* wproj = (const float*)d_in[5];
    const float* bproj = (const float*)d_in[6];
    const float* ln2g  = (const float*)d_in[7];
    const float* ln2b  = (const float*)d_in[8];
    const float* wfc   = (const float*)d_in[9];
    const float* bfc   = (const float*)d_in[10];
    const float* wfc2  = (const float*)d_in[11];
    const float* bfc2  = (const float*)d_in[12];
    float* out = (float*)d_out;

    s16* ws   = (s16*)d_ws;
    s16* wT   = ws;                        // 16,777,216 elems (max weight^T)
    s16* qbuf = wT + 16777216;             // 8,388,608
    s16* kbuf = qbuf + 8388608;            // 8,388,608
    s16* vbuf = kbuf + 8388608;            // 8,388,608 (transposed V)
    s16* hbuf = vbuf + 8388608;            // 8,388,608 (LN1 out; reused as attn y)
    s16* ybuf  = hbuf;
    s16* h2buf = qbuf;
    s16* gbuf  = kbuf;

    // 1) LN1
    ln_kernel<<<4096, 256, 0, stream>>>(x, ln1g, ln1b, hbuf);
    // 2) QKV GEMM: BM=128 -> 768 blocks = exactly 3/CU balanced (scatter q/k/v, v transposed)
    transpose_convert<<<dim3(6144 / 32, 2048 / 32), dim3(32, 8), 0, stream>>>(wattn, wT, 2048, 6144);
    gemm2p<128, 256, 0><<<dim3(6144 / 256, 4096 / 128), 512, 0, stream>>>(
        hbuf, wT, battn, MTOK, 6144, 2048, nullptr, nullptr, qbuf, kbuf, vbuf);
    // 3) attention
    attn_kernel<<<1024, 256, 0, stream>>>(qbuf, kbuf, vbuf, ybuf);
    // 4) proj (+residual, fp32 -> d_out)
    transpose_convert<<<dim3(2048 / 32, 2048 / 32), dim3(32, 8), 0, stream>>>(wproj, wT, 2048, 2048);
    gemm2p<256, 128, 1><<<dim3(2048 / 128, 4096 / 256), 512, 0, stream>>>(
        ybuf, wT, bproj, MTOK, 2048, 2048, out, x, nullptr, nullptr, nullptr);
    // 5) LN2
    ln_kernel<<<4096, 256, 0, stream>>>(out, ln2g, ln2b, h2buf);
    // 6) fc (+gelu, bf16)
    transpose_convert<<<dim3(8192 / 32, 2048 / 32), dim3(32, 8), 0, stream>>>(wfc, wT, 2048, 8192);
    gemm2p<256, 256, 2><<<dim3(8192 / 256, 4096 / 256), 512, 0, stream>>>(
        h2buf, wT, bfc, MTOK, 8192, 2048, nullptr, nullptr, gbuf, nullptr, nullptr);
    // 7) fc2 (+residual, fp32; reads+overwrites d_out per-element)
    transpose_convert<<<dim3(2048 / 32, 8192 / 32), dim3(32, 8), 0, stream>>>(wfc2, wT, 8192, 2048);
    gemm2p<256, 128, 1><<<dim3(2048 / 128, 4096 / 256), 512, 0, stream>>>(
        gbuf, wT, bfc2, MTOK, 2048, 8192, out, out, nullptr, nullptr, nullptr);
}